// Round 1
// 403.153 us; speedup vs baseline: 1.0123x; 1.0123x over previous
//
#include <hip/hip_runtime.h>

// InstanceWiseAveragePooling on MI355X — 2-pass, class codes compressed to 2 bits.
//
// out[p,ch] = mean over ALL feats elements (3 channels, whole batch) whose
// pixel's inst == inst[p]. Classes disjoint, cover all pixels (inst in {0,1,2}).
//
// Pass 1 (reduce_pack_k, 2048 blocks x 256 thr):
//   grid-stride over pixel-quads; per-thread double sums + uint counts per
//   class; wave-shuffle + LDS reduce -> per-block partials in d_ws.
//   ALSO packs the 4 class ids of each quad into ONE byte (2 bits/pixel) ->
//   codes[] (npix/4 bytes = 4.2 MB), so pass 2 never re-reads inst (67 MB).
// Pass 2 (mean_scatter_k, 2048 blocks x 256 thr):
//   every block independently reduces the 2048x3 partials (74 KB, L2-served,
//   ~4us total) -> mean[3] in LDS; then grid-stride scatter:
//   out[3p..3p+2] = mean[code(p)], float4 stores, codes read as bytes.
//
// HBM traffic: 201.3 (feats) + 67.1 (inst) + 4.2 (codes w) + 4.2 (codes r)
//            + 201.3 (out) = ~478 MB  (was ~537 MB with the inst re-read).

#define RBLK 2048

__device__ inline double wred_d(double v) {
#pragma unroll
    for (int off = 32; off; off >>= 1) v += __shfl_down(v, off, 64);
    return v;
}
__device__ inline unsigned wred_u(unsigned v) {
#pragma unroll
    for (int off = 32; off; off >>= 1) v += __shfl_down(v, off, 64);
    return v;
}

__global__ __launch_bounds__(256) void reduce_pack_k(const float* __restrict__ feats,
                                                     const int* __restrict__ inst,
                                                     double* __restrict__ psum,
                                                     unsigned* __restrict__ pcnt,
                                                     unsigned char* __restrict__ codes,
                                                     int npix4) {
    int tid = blockIdx.x * 256 + threadIdx.x;
    int stride = gridDim.x * 256;
    double s0 = 0.0, s1 = 0.0, s2 = 0.0;
    unsigned c0 = 0, c1 = 0, c2 = 0;
    const int4* inst4 = (const int4*)inst;
    for (int i = tid; i < npix4; i += stride) {
        int4 cls = inst4[i];
        const float4* f = (const float4*)(feats + (size_t)i * 12);
        float4 a = f[0], b = f[1], c = f[2];
        // pixel 0: a.x a.y a.z | pixel 1: a.w b.x b.y
        // pixel 2: b.z b.w c.x | pixel 3: c.y c.z c.w
        double d0 = (double)(a.x + a.y + a.z);
        double d1 = (double)(a.w + b.x + b.y);
        double d2 = (double)(b.z + b.w + c.x);
        double d3 = (double)(c.y + c.z + c.w);
        s0 += (cls.x == 0) ? d0 : 0.0;
        s1 += (cls.x == 1) ? d0 : 0.0;
        s2 += (cls.x == 2) ? d0 : 0.0;
        s0 += (cls.y == 0) ? d1 : 0.0;
        s1 += (cls.y == 1) ? d1 : 0.0;
        s2 += (cls.y == 2) ? d1 : 0.0;
        s0 += (cls.z == 0) ? d2 : 0.0;
        s1 += (cls.z == 1) ? d2 : 0.0;
        s2 += (cls.z == 2) ? d2 : 0.0;
        s0 += (cls.w == 0) ? d3 : 0.0;
        s1 += (cls.w == 1) ? d3 : 0.0;
        s2 += (cls.w == 2) ? d3 : 0.0;
        c0 += (unsigned)(cls.x == 0) + (unsigned)(cls.y == 0) +
              (unsigned)(cls.z == 0) + (unsigned)(cls.w == 0);
        c1 += (unsigned)(cls.x == 1) + (unsigned)(cls.y == 1) +
              (unsigned)(cls.z == 1) + (unsigned)(cls.w == 1);
        c2 += (unsigned)(cls.x == 2) + (unsigned)(cls.y == 2) +
              (unsigned)(cls.z == 2) + (unsigned)(cls.w == 2);
        // 2-bit class codes for the 4 pixels of this quad, one byte per quad.
        codes[i] = (unsigned char)((cls.x & 3) | ((cls.y & 3) << 2) |
                                   ((cls.z & 3) << 4) | ((cls.w & 3) << 6));
    }
    s0 = wred_d(s0); s1 = wred_d(s1); s2 = wred_d(s2);
    c0 = wred_u(c0); c1 = wred_u(c1); c2 = wred_u(c2);

    __shared__ double ls[4][3];
    __shared__ unsigned lc[4][3];
    int wid = threadIdx.x >> 6;
    int lane = threadIdx.x & 63;
    if (lane == 0) {
        ls[wid][0] = s0; ls[wid][1] = s1; ls[wid][2] = s2;
        lc[wid][0] = c0; lc[wid][1] = c1; lc[wid][2] = c2;
    }
    __syncthreads();
    if (threadIdx.x < 3) {
        int c = threadIdx.x;
        double s = ls[0][c] + ls[1][c] + ls[2][c] + ls[3][c];
        unsigned cc = lc[0][c] + lc[1][c] + lc[2][c] + lc[3][c];
        psum[blockIdx.x * 3 + c] = s;
        pcnt[blockIdx.x * 3 + c] = cc;
    }
}

__global__ __launch_bounds__(256) void mean_scatter_k(const double* __restrict__ psum,
                                                      const unsigned* __restrict__ pcnt,
                                                      const unsigned char* __restrict__ codes,
                                                      float* __restrict__ out,
                                                      int npix4) {
    // Phase 1: every block independently reduces the RBLK partials -> mean[3].
    // 74 KB per block, L2-served; removes the separate finalize dispatch.
    double s0 = 0.0, s1 = 0.0, s2 = 0.0;
    unsigned c0 = 0, c1 = 0, c2 = 0;
    for (int i = threadIdx.x; i < RBLK; i += 256) {
        s0 += psum[i * 3 + 0]; s1 += psum[i * 3 + 1]; s2 += psum[i * 3 + 2];
        c0 += pcnt[i * 3 + 0]; c1 += pcnt[i * 3 + 1]; c2 += pcnt[i * 3 + 2];
    }
    s0 = wred_d(s0); s1 = wred_d(s1); s2 = wred_d(s2);
    c0 = wred_u(c0); c1 = wred_u(c1); c2 = wred_u(c2);

    __shared__ double ls[4][3];
    __shared__ unsigned lc[4][3];
    __shared__ float smean[3];
    int wid = threadIdx.x >> 6;
    int lane = threadIdx.x & 63;
    if (lane == 0) {
        ls[wid][0] = s0; ls[wid][1] = s1; ls[wid][2] = s2;
        lc[wid][0] = c0; lc[wid][1] = c1; lc[wid][2] = c2;
    }
    __syncthreads();
    if (threadIdx.x < 3) {
        int c = threadIdx.x;
        double s = ls[0][c] + ls[1][c] + ls[2][c] + ls[3][c];
        unsigned cc = lc[0][c] + lc[1][c] + lc[2][c] + lc[3][c];
        // count includes the 3-channel broadcast in the reference
        smean[c] = (float)(s / (3.0 * (double)cc));
    }
    __syncthreads();
    float m0 = smean[0], m1 = smean[1], m2 = smean[2];

    // Phase 2: grid-stride scatter using the packed 2-bit codes (4.2 MB
    // instead of the 67 MB inst re-read).
    int tid = blockIdx.x * 256 + threadIdx.x;
    int stride = gridDim.x * 256;
    for (int i = tid; i < npix4; i += stride) {
        unsigned cb = codes[i];
        unsigned x = cb & 3, y = (cb >> 2) & 3, z = (cb >> 4) & 3, w = (cb >> 6) & 3;
        float vx = (x == 1) ? m1 : ((x == 2) ? m2 : m0);
        float vy = (y == 1) ? m1 : ((y == 2) ? m2 : m0);
        float vz = (z == 1) ? m1 : ((z == 2) ? m2 : m0);
        float vw = (w == 1) ? m1 : ((w == 2) ? m2 : m0);
        float4* o = (float4*)(out + (size_t)i * 12);
        o[0] = make_float4(vx, vx, vx, vy);
        o[1] = make_float4(vy, vy, vz, vz);
        o[2] = make_float4(vz, vw, vw, vw);
    }
}

extern "C" void kernel_launch(void* const* d_in, const int* in_sizes, int n_in,
                              void* d_out, int out_size, void* d_ws, size_t ws_size,
                              hipStream_t stream) {
    const float* feats = (const float*)d_in[0];
    const int* inst = (const int*)d_in[1];
    float* out = (float*)d_out;

    int npix = in_sizes[1];        // 16*1024*1024, divisible by 4
    int npix4 = npix >> 2;

    double* psum = (double*)d_ws;                       // RBLK*3 doubles
    unsigned* pcnt = (unsigned*)(psum + RBLK * 3);      // RBLK*3 uints
    unsigned char* codes = (unsigned char*)(pcnt + RBLK * 3); // npix4 bytes

    reduce_pack_k<<<RBLK, 256, 0, stream>>>(feats, inst, psum, pcnt, codes, npix4);
    mean_scatter_k<<<RBLK, 256, 0, stream>>>(psum, pcnt, codes, out, npix4);
}